// Round 3
// baseline (2468.008 us; speedup 1.0000x reference)
//
#include <hip/hip_runtime.h>
#include <hip/hip_bf16.h>

#define T_TOK 4096
#define HID   2048
#define FFN   7168
#define NEXP  8
#define BM    128
#define BN    128
#define BK    64
#define MT    12            // max m-tiles per expert (covers counts <= 1536)
#define NPAIR (T_TOK * 2)

typedef __attribute__((ext_vector_type(8))) short bf16x8;
typedef __attribute__((ext_vector_type(4))) short bf16x4;
typedef __attribute__((ext_vector_type(4))) float f32x4;

union F4 { float4 v; float f[4]; };

// RNE bf16 round, no NaN path (inputs finite)
__device__ __forceinline__ short f2bfs(float f) {
    unsigned u = __float_as_uint(f);
    return (short)((u + 0x7FFFu + ((u >> 16) & 1u)) >> 16);
}
__device__ __forceinline__ float bf2f(short s) {
    return __uint_as_float(((unsigned)(unsigned short)s) << 16);
}
// LDS swizzle: row-major [row][64 bf16] stride 128B; XOR bits 4-6
__device__ __forceinline__ unsigned swzu(int row) {
    return (unsigned)(((row ^ (row >> 3)) & 7) << 4);
}

// ---------------- Router ----------------
__global__ __launch_bounds__(256) void moe_router(
    const float* __restrict__ x, const float* __restrict__ gw,
    int* __restrict__ counts, int* __restrict__ sel0, int* __restrict__ sel1,
    float* __restrict__ w0o, float* __restrict__ w1o)
{
    int wave = threadIdx.x >> 6, lane = threadIdx.x & 63;
    int t = blockIdx.x * 4 + wave;
    const float* xr = x + (size_t)t * HID;
    float acc[NEXP];
#pragma unroll
    for (int e = 0; e < NEXP; ++e) acc[e] = 0.f;
    for (int i = 0; i < HID / 64; ++i) {
        int k = lane + i * 64;
        float xv = xr[k];
        const float4* g = reinterpret_cast<const float4*>(gw + (size_t)k * NEXP);
        float4 g0 = g[0], g1 = g[1];
        acc[0] += xv * g0.x; acc[1] += xv * g0.y; acc[2] += xv * g0.z; acc[3] += xv * g0.w;
        acc[4] += xv * g1.x; acc[5] += xv * g1.y; acc[6] += xv * g1.z; acc[7] += xv * g1.w;
    }
#pragma unroll
    for (int e = 0; e < NEXP; ++e) {
        float v = acc[e];
#pragma unroll
        for (int s = 32; s > 0; s >>= 1) v += __shfl_xor(v, s);
        acc[e] = v;
    }
    if (lane == 0) {
        float mx = acc[0];
        for (int e = 1; e < NEXP; ++e) mx = fmaxf(mx, acc[e]);
        float p[NEXP];
        for (int e = 0; e < NEXP; ++e) p[e] = __expf(acc[e] - mx);
        int e0 = 0;
        for (int e = 1; e < NEXP; ++e) if (p[e] > p[e0]) e0 = e;
        int e1 = (e0 == 0) ? 1 : 0;
        for (int e = 0; e < NEXP; ++e) if (e != e0 && p[e] > p[e1]) e1 = e;
        float rs = p[e0] + p[e1];
        sel0[t] = e0; sel1[t] = e1;
        w0o[t] = p[e0] / rs; w1o[t] = p[e1] / rs;
        atomicAdd(&counts[e0], 1); atomicAdd(&counts[e1], 1);
    }
}

// ---------------- bases (prefix sum over 8 counts) ----------------
__global__ void moe_bases(const int* __restrict__ counts, int* __restrict__ bases)
{
    if (threadIdx.x == 0 && blockIdx.x == 0) {
        int b = 0;
        for (int e = 0; e < NEXP; ++e) { bases[e] = b; b += counts[e]; }
    }
}

// ---------------- Deterministic scatter ----------------
__global__ __launch_bounds__(256) void moe_scatter(
    const int* __restrict__ sel0, const int* __restrict__ sel1,
    const float* __restrict__ w0, const float* __restrict__ w1,
    const int* __restrict__ bases, int* __restrict__ pairTok, float* __restrict__ pairW)
{
    int e = blockIdx.x;
    __shared__ int wsum[4];
    __shared__ int runningS;
    int tid = threadIdx.x, wave = tid >> 6, lane = tid & 63;
    if (tid == 0) runningS = bases[e];
    __syncthreads();
    for (int i0 = 0; i0 < T_TOK; i0 += 256) {
        int t = i0 + tid;
        bool f0 = (sel0[t] == e), f1 = (sel1[t] == e);
        bool sel = f0 || f1;
        unsigned long long mm = __ballot(sel);
        if (lane == 0) wsum[wave] = __popcll(mm);
        __syncthreads();
        int woff = 0;
#pragma unroll
        for (int w = 0; w < 4; ++w) if (w < wave) woff += wsum[w];
        int tot = wsum[0] + wsum[1] + wsum[2] + wsum[3];
        int pre = __popcll(mm & ((1ull << lane) - 1ull));
        if (sel) {
            int pos = runningS + woff + pre;
            pairTok[pos] = t;
            pairW[pos] = f0 ? w0[t] : w1[t];
        }
        __syncthreads();
        if (tid == 0) runningS += tot;
        __syncthreads();
    }
}

// ---------------- GEMM1 (single matrix): hout = [silu](x @ W) as bf16 ----------------
__global__ __launch_bounds__(256, 3) void moe_g1(
    const float* __restrict__ x, const float* __restrict__ Wall,
    const int* __restrict__ counts, const int* __restrict__ bases,
    const int* __restrict__ pairTok, __hip_bfloat16* __restrict__ hout,
    int doSilu, int gn0base, int Fc, int NB)
{
    // XCD pair-major decomposition: all MT m-slots of a (e,n0) pair on one XCD
    int L = blockIdx.x;
    int xcd = L & 7, sidx = L >> 3;
    int pg = sidx / MT, m = sidx - pg * MT;
    int p = pg * 8 + xcd;
    int e = p / NB, nb = p - e * NB;
    int cnt = counts[e];
    int m0 = m * BM;
    if (m0 >= cnt) return;
    int base = bases[e];
    int rows = cnt - m0; if (rows > BM) rows = BM;
    int gn0 = gn0base + nb * BN;

    __shared__ __align__(16) short As[BM * BK];
    __shared__ __align__(16) short Bs[BN * BK];
    __shared__ int tokS[BM];

    int tid = threadIdx.x;
    if (tid < BM) tokS[tid] = (tid < rows) ? pairTok[base + m0 + tid] : pairTok[base];
    __syncthreads();

    int lane = tid & 63, wave = tid >> 6;
    int wm = (wave >> 1) * 64, wn = (wave & 1) * 64;

    f32x4 acc[4][4];
#pragma unroll
    for (int i = 0; i < 4; ++i)
#pragma unroll
        for (int j = 0; j < 4; ++j) acc[i][j] = (f32x4){0.f, 0.f, 0.f, 0.f};

    // A staging: thread covers rows ar+32c, 8 floats each; pre-swizzled global col -> linear LDS store
    int ar = tid >> 3;
    const float* xp[4];
    unsigned astb[4];
#pragma unroll
    for (int c = 0; c < 4; ++c) {
        int row = ar + c * 32;
        int u = (row ^ (row >> 3)) & 7;
        xp[c] = x + (size_t)tokS[row] * HID + 8 * ((tid & 7) ^ u);
        astb[c] = (unsigned)(row * 128 + (tid & 7) * 16);
    }

    // B staging: thread transposes two 4x4 micro-blocks (k-groups bk4, bk4+32)
    int bk4 = (tid >> 5) * 4;
    int bn4 = (tid & 31) * 4;
    const float* wr0 = Wall + (size_t)e * HID * FFN + (size_t)bk4 * FFN + gn0 + bn4;
    const float* wr1 = wr0 + (size_t)32 * FFN;
    unsigned bstb[2][4];
#pragma unroll
    for (int it = 0; it < 2; ++it)
#pragma unroll
        for (int c = 0; c < 4; ++c) {
            int nn = bn4 + c;
            bstb[it][c] = (unsigned)(nn * 128) + ((unsigned)((bk4 + it * 32) * 2) ^ swzu(nn));
        }

    // fragment read bases
    unsigned arb[4], ars[4], brb[4], brs[4];
#pragma unroll
    for (int i = 0; i < 4; ++i) {
        int rA = wm + i * 16 + (lane & 15);
        arb[i] = (unsigned)(rA * 128); ars[i] = swzu(rA);
        int rB = wn + i * 16 + (lane & 15);
        brb[i] = (unsigned)(rB * 128); brs[i] = swzu(rB);
    }

    F4 bpf[2][4];
#pragma unroll
    for (int r = 0; r < 4; ++r) {
        bpf[0][r].v = *reinterpret_cast<const float4*>(wr0 + (size_t)r * FFN);
        bpf[1][r].v = *reinterpret_cast<const float4*>(wr1 + (size_t)r * FFN);
    }
    wr0 += (size_t)BK * FFN; wr1 += (size_t)BK * FFN;

#pragma unroll 1
    for (int kt = 0; kt < HID / BK; ++kt) {
        // issue A loads
        float4 a0[4], a1[4];
#pragma unroll
        for (int c = 0; c < 4; ++c) {
            a0[c] = *reinterpret_cast<const float4*>(xp[c]);
            a1[c] = *reinterpret_cast<const float4*>(xp[c] + 4);
            xp[c] += BK;
        }
        // B: cvt + transposed swizzled store from prefetched regs
#pragma unroll
        for (int it = 0; it < 2; ++it)
#pragma unroll
            for (int c = 0; c < 4; ++c) {
                bf16x4 v = { f2bfs(bpf[it][0].f[c]), f2bfs(bpf[it][1].f[c]),
                             f2bfs(bpf[it][2].f[c]), f2bfs(bpf[it][3].f[c]) };
                *reinterpret_cast<bf16x4*>(reinterpret_cast<char*>(Bs) + bstb[it][c]) = v;
            }
        // A: cvt + linear store
#pragma unroll
        for (int c = 0; c < 4; ++c) {
            union { bf16x8 v; short s[8]; } u;
            u.s[0] = f2bfs(a0[c].x); u.s[1] = f2bfs(a0[c].y);
            u.s[2] = f2bfs(a0[c].z); u.s[3] = f2bfs(a0[c].w);
            u.s[4] = f2bfs(a1[c].x); u.s[5] = f2bfs(a1[c].y);
            u.s[6] = f2bfs(a1[c].z); u.s[7] = f2bfs(a1[c].w);
            *reinterpret_cast<bf16x8*>(reinterpret_cast<char*>(As) + astb[c]) = u.v;
        }
        __syncthreads();
        // prefetch next-k B while computing
        if (kt + 1 < HID / BK) {
#pragma unroll
            for (int r = 0; r < 4; ++r) {
                bpf[0][r].v = *reinterpret_cast<const float4*>(wr0 + (size_t)r * FFN);
                bpf[1][r].v = *reinterpret_cast<const float4*>(wr1 + (size_t)r * FFN);
            }
            wr0 += (size_t)BK * FFN; wr1 += (size_t)BK * FFN;
        }
#pragma unroll
        for (int ks = 0; ks < 2; ++ks) {
            unsigned kk2 = (unsigned)(ks * 64 + (lane >> 4) * 16);
            bf16x8 af[4], bfr[4];
#pragma unroll
            for (int i = 0; i < 4; ++i)
                af[i] = *reinterpret_cast<const bf16x8*>(reinterpret_cast<const char*>(As) + (arb[i] + (kk2 ^ ars[i])));
#pragma unroll
            for (int j = 0; j < 4; ++j)
                bfr[j] = *reinterpret_cast<const bf16x8*>(reinterpret_cast<const char*>(Bs) + (brb[j] + (kk2 ^ brs[j])));
#pragma unroll
            for (int i = 0; i < 4; ++i)
#pragma unroll
                for (int j = 0; j < 4; ++j)
                    acc[i][j] = __builtin_amdgcn_mfma_f32_16x16x32_bf16(af[i], bfr[j], acc[i][j], 0, 0, 0);
        }
        __syncthreads();
    }

    int hi = lane >> 4, lo = lane & 15;
    int n0 = gn0 - gn0base;
#pragma unroll
    for (int i = 0; i < 4; ++i) {
#pragma unroll
        for (int q = 0; q < 4; ++q) {
            int rowL = wm + i * 16 + hi * 4 + q;
            if (rowL < rows) {
                __hip_bfloat16* dst = hout + (size_t)(base + m0 + rowL) * Fc + n0;
#pragma unroll
                for (int j = 0; j < 4; ++j) {
                    float z = acc[i][j][q];
                    float hv = doSilu ? (z / (1.f + __expf(-z))) : z;
                    union { short s; __hip_bfloat16 b; } cv; cv.s = f2bfs(hv);
                    dst[wn + j * 16 + lo] = cv.b;
                }
            }
        }
    }
}

// ---------------- GEMM2: out[tok] += w * ((hA*hB) @ W2) ----------------
__global__ __launch_bounds__(256, 3) void moe_g2(
    const __hip_bfloat16* __restrict__ hA, const __hip_bfloat16* __restrict__ hB,
    const float* __restrict__ w2s,
    const int* __restrict__ counts, const int* __restrict__ bases,
    const int* __restrict__ pairTok, const float* __restrict__ pairW,
    float* __restrict__ out, int chunkF0, int Fc)
{
    const int NB2 = HID / BN;  // 16
    int L = blockIdx.x;
    int xcd = L & 7, sidx = L >> 3;
    int pg = sidx / MT, m = sidx - pg * MT;
    int p = pg * 8 + xcd;
    int e = p / NB2, nb = p - e * NB2;
    int cnt = counts[e];
    int m0 = m * BM;
    if (m0 >= cnt) return;
    int base = bases[e];
    int rows = cnt - m0; if (rows > BM) rows = BM;
    int n0 = nb * BN;

    __shared__ __align__(16) short As[BM * BK];
    __shared__ __align__(16) short Bs[BN * BK];
    __shared__ int tokS[BM];
    __shared__ float wS[BM];

    int tid = threadIdx.x;
    if (tid < BM) {
        tokS[tid] = (tid < rows) ? pairTok[base + m0 + tid] : 0;
        wS[tid]   = (tid < rows) ? pairW[base + m0 + tid] : 0.f;
    }
    __syncthreads();

    int lane = tid & 63, wave = tid >> 6;
    int wm = (wave >> 1) * 64, wn = (wave & 1) * 64;

    f32x4 acc[4][4];
#pragma unroll
    for (int i = 0; i < 4; ++i)
#pragma unroll
        for (int j = 0; j < 4; ++j) acc[i][j] = (f32x4){0.f, 0.f, 0.f, 0.f};

    // A staging: h rows (bf16), elementwise hA*hB during stage; pre-swizzled col, linear store
    int ar = tid >> 3;
    const __hip_bfloat16 *hpa[4], *hpb[4];
    unsigned astb[4];
#pragma unroll
    for (int c = 0; c < 4; ++c) {
        int row = ar + c * 32;
        int u = (row ^ (row >> 3)) & 7;
        int pr = (row < rows) ? (base + m0 + row) : base;
        size_t off = (size_t)pr * Fc + 8 * ((tid & 7) ^ u);
        hpa[c] = hA + off; hpb[c] = hB + off;
        astb[c] = (unsigned)(row * 128 + (tid & 7) * 16);
    }

    int bk4 = (tid >> 5) * 4;
    int bn4 = (tid & 31) * 4;
    const float* wr0 = w2s + (size_t)e * FFN * HID + (size_t)(chunkF0 + bk4) * HID + n0 + bn4;
    const float* wr1 = wr0 + (size_t)32 * HID;
    unsigned bstb[2][4];
#pragma unroll
    for (int it = 0; it < 2; ++it)
#pragma unroll
        for (int c = 0; c < 4; ++c) {
            int nn = bn4 + c;
            bstb[it][c] = (unsigned)(nn * 128) + ((unsigned)((bk4 + it * 32) * 2) ^ swzu(nn));
        }

    unsigned arb[4], ars[4], brb[4], brs[4];
#pragma unroll
    for (int i = 0; i < 4; ++i) {
        int rA = wm + i * 16 + (lane & 15);
        arb[i] = (unsigned)(rA * 128); ars[i] = swzu(rA);
        int rB = wn + i * 16 + (lane & 15);
        brb[i] = (unsigned)(rB * 128); brs[i] = swzu(rB);
    }

    F4 bpf[2][4];
#pragma unroll
    for (int r = 0; r < 4; ++r) {
        bpf[0][r].v = *reinterpret_cast<const float4*>(wr0 + (size_t)r * HID);
        bpf[1][r].v = *reinterpret_cast<const float4*>(wr1 + (size_t)r * HID);
    }
    wr0 += (size_t)BK * HID; wr1 += (size_t)BK * HID;

    int NK = Fc / BK;
#pragma unroll 1
    for (int kt = 0; kt < NK; ++kt) {
        bf16x8 va[4], vb[4];
#pragma unroll
        for (int c = 0; c < 4; ++c) {
            va[c] = *reinterpret_cast<const bf16x8*>(hpa[c]);
            vb[c] = *reinterpret_cast<const bf16x8*>(hpb[c]);
            hpa[c] += BK; hpb[c] += BK;
        }
#pragma unroll
        for (int it = 0; it < 2; ++it)
#pragma unroll
            for (int c = 0; c < 4; ++c) {
                bf16x4 v = { f2bfs(bpf[it][0].f[c]), f2bfs(bpf[it][1].f[c]),
                             f2bfs(bpf[it][2].f[c]), f2bfs(bpf[it][3].f[c]) };
                *reinterpret_cast<bf16x4*>(reinterpret_cast<char*>(Bs) + bstb[it][c]) = v;
            }
#pragma unroll
        for (int c = 0; c < 4; ++c) {
            union { bf16x8 v; short s[8]; } u;
#pragma unroll
            for (int j = 0; j < 8; ++j)
                u.s[j] = f2bfs(bf2f(va[c][j]) * bf2f(vb[c][j]));
            *reinterpret_cast<bf16x8*>(reinterpret_cast<char*>(As) + astb[c]) = u.v;
        }
        __syncthreads();
        if (kt + 1 < NK) {
#pragma unroll
            for (int r = 0; r < 4; ++r) {
                bpf[0][r].v = *reinterpret_cast<const float4*>(wr0 + (size_t)r * HID);
                bpf[1][r].v = *reinterpret_cast<const float4*>(wr1 + (size_t)r * HID);
            }
            wr0 += (size_t)BK * HID; wr1 += (size_t)BK * HID;
        }
#pragma unroll
        for (int ks = 0; ks < 2; ++ks) {
            unsigned kk2 = (unsigned)(ks * 64 + (lane >> 4) * 16);
            bf16x8 af[4], bfr[4];
#pragma unroll
            for (int i = 0; i < 4; ++i)
                af[i] = *reinterpret_cast<const bf16x8*>(reinterpret_cast<const char*>(As) + (arb[i] + (kk2 ^ ars[i])));
#pragma unroll
            for (int j = 0; j < 4; ++j)
                bfr[j] = *reinterpret_cast<const bf16x8*>(reinterpret_cast<const char*>(Bs) + (brb[j] + (kk2 ^ brs[j])));
#pragma unroll
            for (int i = 0; i < 4; ++i)
#pragma unroll
                for (int j = 0; j < 4; ++j)
                    acc[i][j] = __builtin_amdgcn_mfma_f32_16x16x32_bf16(af[i], bfr[j], acc[i][j], 0, 0, 0);
        }
        __syncthreads();
    }

    int hi = lane >> 4, lo = lane & 15;
#pragma unroll
    for (int i = 0; i < 4; ++i) {
#pragma unroll
        for (int q = 0; q < 4; ++q) {
            int rowL = wm + i * 16 + hi * 4 + q;
            if (rowL < rows) {
                float wt = wS[rowL];
                float* dst = out + (size_t)tokS[rowL] * HID + n0;
#pragma unroll
                for (int j = 0; j < 4; ++j)
                    atomicAdd(dst + wn + j * 16 + lo, acc[i][j][q] * wt);
            }
        }
    }
}

// ---------------- host ----------------
extern "C" void kernel_launch(void* const* d_in, const int* in_sizes, int n_in,
                              void* d_out, int out_size, void* d_ws, size_t ws_size,
                              hipStream_t stream)
{
    const float* x   = (const float*)d_in[0];
    const float* gw  = (const float*)d_in[1];
    const float* w1s = (const float*)d_in[2];
    const float* w3s = (const float*)d_in[3];
    const float* w2s = (const float*)d_in[4];
    float* out = (float*)d_out;
    char* ws = (char*)d_ws;

    int*   counts  = (int*)(ws + 0);
    int*   bases   = (int*)(ws + 128);
    int*   sel0    = (int*)(ws + 1024);
    int*   sel1    = (int*)(ws + 1024 + 4 * T_TOK);
    float* w0f     = (float*)(ws + 1024 + 8 * T_TOK);
    float* w1f     = (float*)(ws + 1024 + 12 * T_TOK);
    int*   pairTok = (int*)(ws + 1024 + 16 * T_TOK);
    float* pairW   = (float*)(ws + 1024 + 16 * T_TOK + 4 * NPAIR);

    // chunk FFN so two h buffers (silu(t1), t3) fit the workspace
    int NC = 56;
    const int cands[8] = {1, 2, 4, 7, 8, 14, 28, 56};
    for (int i = 0; i < 8; ++i) {
        size_t need = 262144 + 2 * (size_t)NPAIR * (FFN / cands[i]) * 2;
        if (need <= ws_size) { NC = cands[i]; break; }
    }
    int Fc = FFN / NC;
    __hip_bfloat16* hbufA = (__hip_bfloat16*)(ws + 262144);
    __hip_bfloat16* hbufB = hbufA + (size_t)NPAIR * Fc;

    hipMemsetAsync(ws, 0, 1024, stream);
    hipMemsetAsync(d_out, 0, (size_t)out_size * sizeof(float), stream);
    moe_router<<<T_TOK / 4, 256, 0, stream>>>(x, gw, counts, sel0, sel1, w0f, w1f);
    moe_bases<<<1, 64, 0, stream>>>(counts, bases);
    moe_scatter<<<NEXP, 256, 0, stream>>>(sel0, sel1, w0f, w1f, bases, pairTok, pairW);

    int NB = Fc / BN;
    int grid1 = NEXP * NB * MT;          // pair-major, P % 8 == 0 always (NEXP=8)
    int grid2 = NEXP * (HID / BN) * MT;
    for (int c = 0; c < NC; ++c) {
        moe_g1<<<grid1, 256, 0, stream>>>(x, w1s, counts, bases, pairTok, hbufA, 1, c * Fc, Fc, NB);
        moe_g1<<<grid1, 256, 0, stream>>>(x, w3s, counts, bases, pairTok, hbufB, 0, c * Fc, Fc, NB);
        moe_g2<<<grid2, 256, 0, stream>>>(hbufA, hbufB, w2s, counts, bases, pairTok, pairW,
                                          out, c * Fc, Fc);
    }
    (void)in_sizes; (void)n_in;
}

// Round 4
// 1558.109 us; speedup vs baseline: 1.5840x; 1.5840x over previous
//
#include <hip/hip_runtime.h>
#include <hip/hip_bf16.h>

#define T_TOK 4096
#define HID   2048
#define FFN   7168
#define NEXP  8
#define BM    128
#define BN    128
#define BK    64
#define MT    16
#define NPAIR (T_TOK * 2)
#define KT1   (HID / BK)   // 32 k-tiles for GEMM1

typedef __attribute__((ext_vector_type(8))) short bf16x8;
typedef __attribute__((ext_vector_type(4))) short bf16x4;
typedef __attribute__((ext_vector_type(4))) float f32x4;

union F4 { float4 v; float f[4]; };

__device__ __forceinline__ short f2bfs(float f) {
    unsigned u = __float_as_uint(f);
    return (short)((u + 0x7FFFu + ((u >> 16) & 1u)) >> 16);
}
__device__ __forceinline__ unsigned swzu(int row) {
    return (unsigned)(((row ^ (row >> 3)) & 7) << 4);
}
// async global->LDS, 16B per lane; LDS dest wave-uniform, global src per-lane
__device__ __forceinline__ void gl16(const void* g, void* l) {
    __builtin_amdgcn_global_load_lds(
        (const __attribute__((address_space(1))) unsigned int*)g,
        (__attribute__((address_space(3))) unsigned int*)l, 16, 0, 0);
}

// ---------------- Router ----------------
__global__ __launch_bounds__(256) void moe_router(
    const float* __restrict__ x, const float* __restrict__ gw,
    int* __restrict__ counts, int* __restrict__ sel0, int* __restrict__ sel1,
    float* __restrict__ w0o, float* __restrict__ w1o)
{
    int wave = threadIdx.x >> 6, lane = threadIdx.x & 63;
    int t = blockIdx.x * 4 + wave;
    const float* xr = x + (size_t)t * HID;
    float acc[NEXP];
#pragma unroll
    for (int e = 0; e < NEXP; ++e) acc[e] = 0.f;
    for (int i = 0; i < HID / 64; ++i) {
        int k = lane + i * 64;
        float xv = xr[k];
        const float4* g = reinterpret_cast<const float4*>(gw + (size_t)k * NEXP);
        float4 g0 = g[0], g1 = g[1];
        acc[0] += xv * g0.x; acc[1] += xv * g0.y; acc[2] += xv * g0.z; acc[3] += xv * g0.w;
        acc[4] += xv * g1.x; acc[5] += xv * g1.y; acc[6] += xv * g1.z; acc[7] += xv * g1.w;
    }
#pragma unroll
    for (int e = 0; e < NEXP; ++e) {
        float v = acc[e];
#pragma unroll
        for (int s = 32; s > 0; s >>= 1) v += __shfl_xor(v, s);
        acc[e] = v;
    }
    if (lane == 0) {
        float mx = acc[0];
        for (int e = 1; e < NEXP; ++e) mx = fmaxf(mx, acc[e]);
        float p[NEXP];
        for (int e = 0; e < NEXP; ++e) p[e] = __expf(acc[e] - mx);
        int e0 = 0;
        for (int e = 1; e < NEXP; ++e) if (p[e] > p[e0]) e0 = e;
        int e1 = (e0 == 0) ? 1 : 0;
        for (int e = 0; e < NEXP; ++e) if (e != e0 && p[e] > p[e1]) e1 = e;
        float rs = p[e0] + p[e1];
        sel0[t] = e0; sel1[t] = e1;
        w0o[t] = p[e0] / rs; w1o[t] = p[e1] / rs;
        atomicAdd(&counts[e0], 1); atomicAdd(&counts[e1], 1);
    }
}

__global__ void moe_bases(const int* __restrict__ counts, int* __restrict__ bases)
{
    if (threadIdx.x == 0 && blockIdx.x == 0) {
        int b = 0;
        for (int e = 0; e < NEXP; ++e) { bases[e] = b; b += counts[e]; }
    }
}

// ---------------- Deterministic scatter ----------------
__global__ __launch_bounds__(256) void moe_scatter(
    const int* __restrict__ sel0, const int* __restrict__ sel1,
    const float* __restrict__ w0, const float* __restrict__ w1,
    const int* __restrict__ bases, int* __restrict__ pairTok, float* __restrict__ pairW)
{
    int e = blockIdx.x;
    __shared__ int wsum[4];
    __shared__ int runningS;
    int tid = threadIdx.x, wave = tid >> 6, lane = tid & 63;
    if (tid == 0) runningS = bases[e];
    __syncthreads();
    for (int i0 = 0; i0 < T_TOK; i0 += 256) {
        int t = i0 + tid;
        bool f0 = (sel0[t] == e), f1 = (sel1[t] == e);
        bool sel = f0 || f1;
        unsigned long long mm = __ballot(sel);
        if (lane == 0) wsum[wave] = __popcll(mm);
        __syncthreads();
        int woff = 0;
#pragma unroll
        for (int w = 0; w < 4; ++w) if (w < wave) woff += wsum[w];
        int tot = wsum[0] + wsum[1] + wsum[2] + wsum[3];
        int pre = __popcll(mm & ((1ull << lane) - 1ull));
        if (sel) {
            int pos = runningS + woff + pre;
            pairTok[pos] = t;
            pairW[pos] = f0 ? w0[t] : w1[t];
        }
        __syncthreads();
        if (tid == 0) runningS += tot;
        __syncthreads();
    }
}

// ---------------- xperm: gather routed token rows as bf16 ----------------
__global__ __launch_bounds__(256) void moe_xperm(
    const float* __restrict__ x, const int* __restrict__ pairTok,
    short* __restrict__ xperm)
{
    int p = blockIdx.x * 4 + (threadIdx.x >> 6);
    int lane = threadIdx.x & 63;
    const float* s = x + (size_t)pairTok[p] * HID;
    short* d = xperm + (size_t)p * HID;
#pragma unroll
    for (int i = 0; i < HID / 512; ++i) {     // 4 iters, 8 floats/lane
        int k = (i * 64 + lane) * 8;
        float4 f0 = *reinterpret_cast<const float4*>(s + k);
        float4 f1 = *reinterpret_cast<const float4*>(s + k + 4);
        union { bf16x8 v; short sh[8]; } u;
        u.sh[0] = f2bfs(f0.x); u.sh[1] = f2bfs(f0.y); u.sh[2] = f2bfs(f0.z); u.sh[3] = f2bfs(f0.w);
        u.sh[4] = f2bfs(f1.x); u.sh[5] = f2bfs(f1.y); u.sh[6] = f2bfs(f1.z); u.sh[7] = f2bfs(f1.w);
        *reinterpret_cast<bf16x8*>(d + k) = u.v;
    }
}

// ---------------- retile: fp32 [K][N] -> bf16 swizzled [n][k] 16KB slabs ----------------
// slab L=((e*NB+nb)*KT+kt) holds rows n0..n0+127, k0..k0+63, pos = n*128B + (k*2 ^ swz(n))
__global__ __launch_bounds__(256) void moe_retile(
    const float* __restrict__ src, size_t eStride, int rowStride,
    short* __restrict__ dst, int NB, int KT)
{
    int L = blockIdx.x;
    int e = L / (NB * KT);
    int r = L - e * (NB * KT);
    int nb = r / KT, kt = r - nb * KT;
    const float* s0 = src + (size_t)e * eStride + (size_t)(kt * 64) * rowStride + nb * 128;
    __shared__ __align__(16) short S[8192];
    int t = threadIdx.x;
#pragma unroll
    for (int uu = 0; uu < 2; ++uu) {
        int u = t + uu * 256;
        int kq = u >> 5, nq = u & 31;     // 4x4 unit at (kq*4, nq*4)
        const float* p = s0 + (size_t)(kq * 4) * rowStride + nq * 4;
        F4 r0, r1, r2, r3;
        r0.v = *reinterpret_cast<const float4*>(p);
        r1.v = *reinterpret_cast<const float4*>(p + rowStride);
        r2.v = *reinterpret_cast<const float4*>(p + 2 * (size_t)rowStride);
        r3.v = *reinterpret_cast<const float4*>(p + 3 * (size_t)rowStride);
#pragma unroll
        for (int c = 0; c < 4; ++c) {
            int n = nq * 4 + c;
            bf16x4 v = { f2bfs(r0.f[c]), f2bfs(r1.f[c]), f2bfs(r2.f[c]), f2bfs(r3.f[c]) };
            *reinterpret_cast<bf16x4*>(reinterpret_cast<char*>(S) +
                (unsigned)(n * 128) + ((unsigned)(kq * 8) ^ swzu(n))) = v;
        }
    }
    __syncthreads();
    char* d = reinterpret_cast<char*>(dst) + (size_t)L * 16384;
    const char* sc = reinterpret_cast<const char*>(S);
#pragma unroll
    for (int i = 0; i < 4; ++i)
        *reinterpret_cast<bf16x8*>(d + t * 16 + i * 4096) =
            *reinterpret_cast<const bf16x8*>(sc + t * 16 + i * 4096);
}

// ---------------- GEMM1: h = silu(x@W1)*(x@W3), pure global_load_lds staging ----------------
__global__ __launch_bounds__(256, 2) void moe_g1(
    const short* __restrict__ xperm, const short* __restrict__ w1r, const short* __restrict__ w3r,
    const int* __restrict__ counts, const int* __restrict__ bases,
    short* __restrict__ hbuf, int NBc, int Fc)
{
    int L = blockIdx.x;
    int e = L & 7;                       // expert <-> XCD binding
    int i = L >> 3;
    int nb = i / MT, m = i - nb * MT;    // m innermost: sibling m-tiles consecutive
    int cnt = counts[e];
    int m0 = m * BM;
    if (m0 >= cnt) return;
    int base = bases[e];
    int rows = cnt - m0; if (rows > BM) rows = BM;

    __shared__ __align__(16) short As[8192], B1s[8192], B3s[8192];

    int tid = threadIdx.x, lane = tid & 63, w = tid >> 6;
    int wm = (w >> 1) * 64, wn = (w & 1) * 64;

    // A per-lane swizzle-baked sources (wave w stages rows [w*32, w*32+32))
    const char* aSrc[4];
#pragma unroll
    for (int j = 0; j < 4; ++j) {
        int row = w * 32 + j * 8 + (lane >> 3);
        aSrc[j] = reinterpret_cast<const char*>(xperm) +
                  (size_t)(base + m0 + row) * (HID * 2) +
                  (((unsigned)((lane & 7) * 16)) ^ swzu(row));
    }
    const char* b1Src = reinterpret_cast<const char*>(w1r) +
                        (size_t)(e * NBc + nb) * KT1 * 16384 + w * 4096 + lane * 16;
    const char* b3Src = reinterpret_cast<const char*>(w3r) +
                        (size_t)(e * NBc + nb) * KT1 * 16384 + w * 4096 + lane * 16;
    char* aDst  = reinterpret_cast<char*>(As)  + w * 4096;
    char* b1Dst = reinterpret_cast<char*>(B1s) + w * 4096;
    char* b3Dst = reinterpret_cast<char*>(B3s) + w * 4096;

    f32x4 acc1[4][4], acc3[4][4];
#pragma unroll
    for (int a = 0; a < 4; ++a)
#pragma unroll
        for (int b = 0; b < 4; ++b) { acc1[a][b] = (f32x4){0.f,0.f,0.f,0.f}; acc3[a][b] = (f32x4){0.f,0.f,0.f,0.f}; }

    unsigned arb[4], ars[4], brb[4], brs[4];
#pragma unroll
    for (int a = 0; a < 4; ++a) {
        int rA = wm + a * 16 + (lane & 15);
        arb[a] = (unsigned)(rA * 128); ars[a] = swzu(rA);
        int rB = wn + a * 16 + (lane & 15);
        brb[a] = (unsigned)(rB * 128); brs[a] = swzu(rB);
    }

#pragma unroll 1
    for (int kt = 0; kt < KT1; ++kt) {
#pragma unroll
        for (int j = 0; j < 4; ++j) {
            gl16(aSrc[j] + (size_t)kt * 128, aDst + j * 1024);
            gl16(b1Src + (size_t)kt * 16384 + j * 1024, b1Dst + j * 1024);
            gl16(b3Src + (size_t)kt * 16384 + j * 1024, b3Dst + j * 1024);
        }
        __syncthreads();
#pragma unroll
        for (int ks = 0; ks < 2; ++ks) {
            unsigned kk2 = (unsigned)(ks * 64 + (lane >> 4) * 16);
            bf16x8 af[4], b1f[4], b3f[4];
#pragma unroll
            for (int a = 0; a < 4; ++a)
                af[a] = *reinterpret_cast<const bf16x8*>(reinterpret_cast<const char*>(As) + (arb[a] + (kk2 ^ ars[a])));
#pragma unroll
            for (int b = 0; b < 4; ++b) {
                b1f[b] = *reinterpret_cast<const bf16x8*>(reinterpret_cast<const char*>(B1s) + (brb[b] + (kk2 ^ brs[b])));
                b3f[b] = *reinterpret_cast<const bf16x8*>(reinterpret_cast<const char*>(B3s) + (brb[b] + (kk2 ^ brs[b])));
            }
#pragma unroll
            for (int a = 0; a < 4; ++a)
#pragma unroll
                for (int b = 0; b < 4; ++b) {
                    acc1[a][b] = __builtin_amdgcn_mfma_f32_16x16x32_bf16(af[a], b1f[b], acc1[a][b], 0, 0, 0);
                    acc3[a][b] = __builtin_amdgcn_mfma_f32_16x16x32_bf16(af[a], b3f[b], acc3[a][b], 0, 0, 0);
                }
        }
        __syncthreads();
    }

    int hi = lane >> 4, lo = lane & 15;
#pragma unroll
    for (int a = 0; a < 4; ++a) {
#pragma unroll
        for (int q = 0; q < 4; ++q) {
            int rowL = wm + a * 16 + hi * 4 + q;
            if (rowL < rows) {
                short* dst = hbuf + (size_t)(base + m0 + rowL) * Fc + nb * 128;
#pragma unroll
                for (int b = 0; b < 4; ++b) {
                    float z = acc1[a][b][q];
                    float hv = (z / (1.f + __expf(-z))) * acc3[a][b][q];
                    dst[wn + b * 16 + lo] = f2bfs(hv);
                }
            }
        }
    }
}

// ---------------- GEMM2: out[tok] += w * (h @ W2) ----------------
__global__ __launch_bounds__(256, 2) void moe_g2(
    const short* __restrict__ hbuf, const short* __restrict__ w2r,
    const int* __restrict__ counts, const int* __restrict__ bases,
    const int* __restrict__ pairTok, const float* __restrict__ pairW,
    float* __restrict__ out, int Fc, int KT2)
{
    const int NB2 = HID / BN;            // 16
    int L = blockIdx.x;
    int e = L & 7;
    int i = L >> 3;
    int nb = i / MT, m = i - nb * MT;
    int cnt = counts[e];
    int m0 = m * BM;
    if (m0 >= cnt) return;
    int base = bases[e];
    int rows = cnt - m0; if (rows > BM) rows = BM;

    __shared__ __align__(16) short As[8192], Bs[8192];
    __shared__ int tokS[BM];
    __shared__ float wS[BM];

    int tid = threadIdx.x, lane = tid & 63, w = tid >> 6;
    if (tid < BM) {
        tokS[tid] = (tid < rows) ? pairTok[base + m0 + tid] : 0;
        wS[tid]   = (tid < rows) ? pairW[base + m0 + tid] : 0.f;
    }
    int wm = (w >> 1) * 64, wn = (w & 1) * 64;

    const char* aSrc[4];
#pragma unroll
    for (int j = 0; j < 4; ++j) {
        int row = w * 32 + j * 8 + (lane >> 3);
        aSrc[j] = reinterpret_cast<const char*>(hbuf) +
                  (size_t)(base + m0 + row) * (size_t)(Fc * 2) +
                  (((unsigned)((lane & 7) * 16)) ^ swzu(row));
    }
    const char* bSrc = reinterpret_cast<const char*>(w2r) +
                       (size_t)(e * NB2 + nb) * KT2 * 16384 + w * 4096 + lane * 16;
    char* aDst = reinterpret_cast<char*>(As) + w * 4096;
    char* bDst = reinterpret_cast<char*>(Bs) + w * 4096;

    f32x4 acc[4][4];
#pragma unroll
    for (int a = 0; a < 4; ++a)
#pragma unroll
        for (int b = 0; b < 4; ++b) acc[a][b] = (f32x4){0.f,0.f,0.f,0.f};

    unsigned arb[4], ars[4], brb[4], brs[4];
#pragma unroll
    for (int a = 0; a < 4; ++a) {
        int rA = wm + a * 16 + (lane & 15);
        arb[a] = (unsigned)(rA * 128); ars[a] = swzu(rA);
        int rB = wn + a * 16 + (lane & 15);
        brb[a] = (unsigned)(rB * 128); brs[a] = swzu(rB);
    }
    __syncthreads();   // tokS/wS visible; also aligns staging start

#pragma unroll 1
    for (int kt = 0; kt < KT2; ++kt) {
#pragma unroll
        for (int j = 0; j < 4; ++j) {
            gl16(aSrc[j] + (size_t)kt * 128, aDst + j * 1024);
            gl16(bSrc + (size_t)kt * 16384 + j * 1024, bDst + j * 1024);
        }
        __syncthreads();
#pragma unroll
        for (int ks = 0; ks < 2; ++ks) {
            unsigned kk2 = (unsigned)(ks * 64 + (lane >> 4) * 16);
            bf16x8 af[4], bfr[4];
#pragma unroll
            for (int a = 0; a < 4; ++a)
                af[a] = *reinterpret_cast<const bf16x8*>(reinterpret_cast<const char*>(As) + (arb[a] + (kk2 ^ ars[a])));
#pragma unroll
            for (int b = 0; b < 4; ++b)
                bfr[b] = *reinterpret_cast<const bf16x8*>(reinterpret_cast<const char*>(Bs) + (brb[b] + (kk2 ^ brs[b])));
#pragma unroll
            for (int a = 0; a < 4; ++a)
#pragma unroll
                for (int b = 0; b < 4; ++b)
                    acc[a][b] = __builtin_amdgcn_mfma_f32_16x16x32_bf16(af[a], bfr[b], acc[a][b], 0, 0, 0);
        }
        __syncthreads();
    }

    int hi = lane >> 4, lo = lane & 15;
#pragma unroll
    for (int a = 0; a < 4; ++a) {
#pragma unroll
        for (int q = 0; q < 4; ++q) {
            int rowL = wm + a * 16 + hi * 4 + q;
            if (rowL < rows) {
                float wt = wS[rowL];
                float* dst = out + (size_t)tokS[rowL] * HID + nb * 128;
#pragma unroll
                for (int b = 0; b < 4; ++b)
                    atomicAdd(dst + wn + b * 16 + lo, acc[a][b][q] * wt);
            }
        }
    }
}

// ---------------- host ----------------
extern "C" void kernel_launch(void* const* d_in, const int* in_sizes, int n_in,
                              void* d_out, int out_size, void* d_ws, size_t ws_size,
                              hipStream_t stream)
{
    const float* x   = (const float*)d_in[0];
    const float* gw  = (const float*)d_in[1];
    const float* w1s = (const float*)d_in[2];
    const float* w3s = (const float*)d_in[3];
    const float* w2s = (const float*)d_in[4];
    float* out = (float*)d_out;
    char* ws = (char*)d_ws;

    int*   counts  = (int*)(ws + 0);
    int*   bases   = (int*)(ws + 128);
    int*   sel0    = (int*)(ws + 1024);
    int*   sel1    = (int*)(ws + 1024 + 4 * T_TOK);
    float* w0f     = (float*)(ws + 1024 + 8 * T_TOK);
    float* w1f     = (float*)(ws + 1024 + 12 * T_TOK);
    int*   pairTok = (int*)(ws + 1024 + 16 * T_TOK);                 // 32 KB
    float* pairW   = (float*)(ws + 1024 + 16 * T_TOK + 4 * NPAIR);   // 32 KB

    // pick smallest NC (FFN chunking) whose buffers fit ws
    const int cands[8] = {1, 2, 4, 7, 8, 14, 28, 56};
    int NC = 56;
    for (int ci = 0; ci < 8; ++ci) {
        int nc = cands[ci];
        int NBc = 56 / nc, KT2c = 112 / nc, Fcc = FFN / nc;
        size_t sz13 = (size_t)NEXP * NBc * KT1 * 16384;      // per W1 or W3
        size_t sz2  = (size_t)NEXP * 16 * KT2c * 16384;
        size_t sxp  = (size_t)(NPAIR + BM) * HID * 2;
        size_t shb  = (size_t)(NPAIR + BM) * Fcc * 2;
        if (262144 + 2 * sz13 + sz2 + sxp + shb <= ws_size) { NC = nc; break; }
    }
    int NBc = 56 / NC, KT2c = 112 / NC, Fc = FFN / NC;
    size_t sz13 = (size_t)NEXP * NBc * KT1 * 16384;
    size_t sz2  = (size_t)NEXP * 16 * KT2c * 16384;
    size_t sxp  = (size_t)(NPAIR + BM) * HID * 2;
    short* w1r   = (short*)(ws + 262144);
    short* w3r   = (short*)(ws + 262144 + sz13);
    short* w2r   = (short*)(ws + 262144 + 2 * sz13);
    short* xperm = (short*)(ws + 262144 + 2 * sz13 + sz2);
    short* hbuf  = (short*)(ws + 262144 + 2 * sz13 + sz2 + sxp);

    hipMemsetAsync(ws, 0, 1024, stream);
    hipMemsetAsync(d_out, 0, (size_t)out_size * sizeof(float), stream);
    moe_router<<<T_TOK / 4, 256, 0, stream>>>(x, gw, counts, sel0, sel1, w0f, w1f);
    moe_bases<<<1, 64, 0, stream>>>(counts, bases);
    moe_scatter<<<NEXP, 256, 0, stream>>>(sel0, sel1, w0f, w1f, bases, pairTok, pairW);
    moe_xperm<<<NPAIR / 4, 256, 0, stream>>>(x, pairTok, xperm);

    for (int c = 0; c < NC; ++c) {
        // retile weights for this FFN chunk
        moe_retile<<<NEXP * NBc * KT1, 256, 0, stream>>>(
            w1s + (size_t)c * Fc, (size_t)HID * FFN, FFN, w1r, NBc, KT1);
        moe_retile<<<NEXP * NBc * KT1, 256, 0, stream>>>(
            w3s + (size_t)c * Fc, (size_t)HID * FFN, FFN, w3r, NBc, KT1);
        moe_retile<<<NEXP * 16 * KT2c, 256, 0, stream>>>(
            w2s + (size_t)(c * Fc) * HID, (size_t)FFN * HID, HID, w2r, 16, KT2c);
        moe_g1<<<NEXP * NBc * MT, 256, 0, stream>>>(
            xperm, w1r, w3r, counts, bases, hbuf, NBc, Fc);
        moe_g2<<<NEXP * 16 * MT, 256, 0, stream>>>(
            hbuf, w2r, counts, bases, pairTok, pairW, out, Fc, KT2c);
    }
    (void)in_sizes; (void)n_in;
}